// Round 10
// baseline (269.768 us; speedup 1.0000x reference)
//
#include <hip/hip_runtime.h>
#include <hip/hip_fp16.h>
#include <math.h>

// ---------------------------------------------------------------------------
// PointTransformerNet forward, 6 kernels + memset:
//   memset(count) ; hist+proj1 ; scan ; scatter ; E1+proj2 ; E2+head
//
// R10: edge payload is f32 float2 (E, E*vv) with E = e^{-(a_src+c)} per src
// node. The per-dst factor e^{d_i} cancels in the softmax ratio, so
//   h = relu(dv + (sum E*vv)/(sum E))
// and the edge loop is ONE 8B gather + TWO v_add_f32 per edge. R9 stored E
// in f16 and failed (absmax 0.66): per-channel sigma of a+c reaches ~2.2, the
// tails blow past f16's e^{+-11} range and the clamps distorted dominant
// edges. f32 range e^{+-88} makes clamps unreachable.
//
// R8: fdot2 for fc dots. R6: grid-stride, stage W once per block.
// R5: grid.sync on gfx950 ~200us each (8 XCD L2 flush) -- never.
// ---------------------------------------------------------------------------

#define LOG2E 1.44269504088896340736f

typedef _Float16 hf2 __attribute__((ext_vector_type(2)));
union H2U { __half2 hh; hf2 hf; unsigned u; };

#if defined(__has_builtin)
#if __has_builtin(__builtin_amdgcn_fdot2)
#define HAVE_FDOT2 1
#endif
#endif

__device__ __forceinline__ float fdot2(hf2 a, hf2 b, float c) {
#ifdef HAVE_FDOT2
    return __builtin_amdgcn_fdot2(a, b, c, false);
#else
    return fmaf((float)a.x, (float)b.x, fmaf((float)a.y, (float)b.y, c));
#endif
}

// Payload: (E, E*vv) in full f32. Safety clamp at e^+-60 (unreachable: a+c
// would need ~27 sigma), keeps products finite in f32.
__device__ __forceinline__ float2 pack_payload(float a_plus_c, float vv) {
    float t = fminf(fmaxf(-a_plus_c * LOG2E, -86.6f), 86.6f);
    float E = exp2f(t);
    return make_float2(E, E * vv);
}

// hist (1 atomic/edge, rank recorded) + conv1 payload, grid-strided.
__global__ void __launch_bounds__(256) hist_proj1_kernel(
        const int* __restrict__ dst, int* __restrict__ count, int* __restrict__ rank,
        const float* __restrict__ x, const float* __restrict__ pos,
        const float* __restrict__ W1_src, const float* __restrict__ W1_val,
        const float* __restrict__ W1_pos,
        float2* __restrict__ g1, int N, int E) {
    int gtid = blockIdx.x * 256 + threadIdx.x;
    int gsz = gridDim.x * 256;
    for (int e = gtid; e < E; e += gsz)
        rank[e] = atomicAdd(&count[dst[e]], 1);

    int lane = threadIdx.x & 63, wid = threadIdx.x >> 6;
    float ws0 = W1_src[lane], ws1 = W1_src[64 + lane], ws2 = W1_src[128 + lane];
    float wv0 = W1_val[lane], wv1 = W1_val[64 + lane], wv2 = W1_val[128 + lane];
    float wp0 = W1_pos[lane], wp1 = W1_pos[64 + lane], wp2 = W1_pos[128 + lane];
    int nwav = gridDim.x * 4;
    for (int node = blockIdx.x * 4 + wid; node < N; node += nwav) {
        float x0 = x[node * 3 + 0], x1 = x[node * 3 + 1], x2 = x[node * 3 + 2];
        float p0 = pos[node * 3 + 0], p1 = pos[node * 3 + 1], p2 = pos[node * 3 + 2];
        float as = fmaf(x0, ws0, fmaf(x1, ws1, x2 * ws2));
        float vv = fmaf(x0, wv0, fmaf(x1, wv1, x2 * wv2));
        float cc = fmaf(p0, wp0, fmaf(p1, wp1, p2 * wp2));
        g1[node * 64 + lane] = pack_payload(as + cc, vv - cc);
    }
}

// Single-kernel scan: block b redundantly reduces count[0 .. b*1024) for its
// base, then emits its 1024-chunk's exclusive prefix.
__global__ void __launch_bounds__(256) scan_kernel(
        const int* __restrict__ count, int* __restrict__ offsets, int n, int nsb) {
    __shared__ int red[4];
    __shared__ int wpre[4];
    int tid = threadIdx.x, lane = tid & 63, wid = tid >> 6;
    int lim = blockIdx.x * 1024;
    int s = 0;
    for (int i = tid * 4; i < lim; i += 1024) {
        int4 c = *(const int4*)&count[i];
        s += c.x + c.y + c.z + c.w;
    }
    #pragma unroll
    for (int off = 32; off >= 1; off >>= 1) s += __shfl_down(s, off);
    if (lane == 0) red[wid] = s;
    __syncthreads();
    int base = red[0] + red[1] + red[2] + red[3];

    int b4 = lim + tid * 4;
    int4 c = make_int4(0, 0, 0, 0);
    if (b4 + 3 < n) {
        c = *(const int4*)&count[b4];
    } else {
        if (b4 + 0 < n) c.x = count[b4 + 0];
        if (b4 + 1 < n) c.y = count[b4 + 1];
        if (b4 + 2 < n) c.z = count[b4 + 2];
    }
    int tsum = c.x + c.y + c.z + c.w;
    int inc = tsum;
    #pragma unroll
    for (int off = 1; off < 64; off <<= 1) {
        int t2 = __shfl_up(inc, off);
        if (lane >= off) inc += t2;
    }
    if (lane == 63) wpre[wid] = inc;
    __syncthreads();
    int wbase = 0;
    for (int q = 0; q < wid; ++q) wbase += wpre[q];
    int excl = base + wbase + (inc - tsum);
    if (b4 + 0 < n) offsets[b4 + 0] = excl;
    if (b4 + 1 < n) offsets[b4 + 1] = excl + c.x;
    if (b4 + 2 < n) offsets[b4 + 2] = excl + c.x + c.y;
    if (b4 + 3 < n) offsets[b4 + 3] = excl + c.x + c.y + c.z;
    if ((int)blockIdx.x == nsb - 1 && tid == 0)
        offsets[n] = base + wpre[0] + wpre[1] + wpre[2] + wpre[3];
}

__global__ void __launch_bounds__(256) scatter_kernel(
        const int* __restrict__ src, const int* __restrict__ dst,
        const int* __restrict__ rank, const int* __restrict__ offsets,
        int* __restrict__ sorted_src, int E) {
    int e = blockIdx.x * 256 + threadIdx.x;
    if (e < E) sorted_src[offsets[dst[e]] + rank[e]] = src[e];
}

// Segment aggregate: returns relu(dv + (sum E*vv)/(sum E)).
// Per edge: one 8B gather + two v_add_f32. 8-deep pipelined, scalar addressing.
__device__ __forceinline__ float edge_node(
        int node, int laneoff,
        const int* __restrict__ offsets, const int* __restrict__ ss,
        const char* __restrict__ gbase, float dv) {
    int beg = offsets[node], end = offsets[node + 1];
    if (beg >= end) return 0.f;           // degree-0: reference gives 0
    float s0 = 0.f, n0 = 0.f, s1 = 0.f, n1 = 0.f;
    int e = beg;
    int aligned = min((beg + 3) & ~3, end);    // peel to 16B alignment of ss
    for (; e < aligned; ++e) {
        int i0 = __builtin_amdgcn_readfirstlane(ss[e]);
        float2 g0 = *(const float2*)(gbase + (((size_t)(unsigned)i0) << 9) + laneoff);
        s0 += g0.x; n0 += g0.y;
    }
    for (; e + 8 <= end; e += 8) {
        int4 ia = *(const int4*)(ss + e);
        int4 ib = *(const int4*)(ss + e + 4);
        int i0 = __builtin_amdgcn_readfirstlane(ia.x);
        int i1 = __builtin_amdgcn_readfirstlane(ia.y);
        int i2 = __builtin_amdgcn_readfirstlane(ia.z);
        int i3 = __builtin_amdgcn_readfirstlane(ia.w);
        int i4 = __builtin_amdgcn_readfirstlane(ib.x);
        int i5 = __builtin_amdgcn_readfirstlane(ib.y);
        int i6 = __builtin_amdgcn_readfirstlane(ib.z);
        int i7 = __builtin_amdgcn_readfirstlane(ib.w);
        float2 g0 = *(const float2*)(gbase + (((size_t)(unsigned)i0) << 9) + laneoff);
        float2 g1 = *(const float2*)(gbase + (((size_t)(unsigned)i1) << 9) + laneoff);
        float2 g2 = *(const float2*)(gbase + (((size_t)(unsigned)i2) << 9) + laneoff);
        float2 g3 = *(const float2*)(gbase + (((size_t)(unsigned)i3) << 9) + laneoff);
        float2 g4 = *(const float2*)(gbase + (((size_t)(unsigned)i4) << 9) + laneoff);
        float2 g5 = *(const float2*)(gbase + (((size_t)(unsigned)i5) << 9) + laneoff);
        float2 g6 = *(const float2*)(gbase + (((size_t)(unsigned)i6) << 9) + laneoff);
        float2 g7 = *(const float2*)(gbase + (((size_t)(unsigned)i7) << 9) + laneoff);
        s0 += g0.x; n0 += g0.y;
        s1 += g1.x; n1 += g1.y;
        s0 += g2.x; n0 += g2.y;
        s1 += g3.x; n1 += g3.y;
        s0 += g4.x; n0 += g4.y;
        s1 += g5.x; n1 += g5.y;
        s0 += g6.x; n0 += g6.y;
        s1 += g7.x; n1 += g7.y;
    }
    for (; e + 4 <= end; e += 4) {
        int4 ia = *(const int4*)(ss + e);
        int i0 = __builtin_amdgcn_readfirstlane(ia.x);
        int i1 = __builtin_amdgcn_readfirstlane(ia.y);
        int i2 = __builtin_amdgcn_readfirstlane(ia.z);
        int i3 = __builtin_amdgcn_readfirstlane(ia.w);
        float2 g0 = *(const float2*)(gbase + (((size_t)(unsigned)i0) << 9) + laneoff);
        float2 g1 = *(const float2*)(gbase + (((size_t)(unsigned)i1) << 9) + laneoff);
        float2 g2 = *(const float2*)(gbase + (((size_t)(unsigned)i2) << 9) + laneoff);
        float2 g3 = *(const float2*)(gbase + (((size_t)(unsigned)i3) << 9) + laneoff);
        s0 += g0.x; n0 += g0.y;
        s1 += g1.x; n1 += g1.y;
        s0 += g2.x; n0 += g2.y;
        s1 += g3.x; n1 += g3.y;
    }
    for (; e < end; ++e) {
        int i0 = __builtin_amdgcn_readfirstlane(ss[e]);
        float2 g0 = *(const float2*)(gbase + (((size_t)(unsigned)i0) << 9) + laneoff);
        s0 += g0.x; n0 += g0.y;
    }
    float s = s0 + s1;
    float r = __builtin_amdgcn_rcpf(s + 1e-37f);
    return fmaxf(fmaf(n0 + n1, r, dv), 0.f);
}

// E1 + proj2 fused, grid-strided. proj2 dot: W2 staged as b128 k-quads
// (src01,src23,val01,val23); h as broadcast b64 pairs; 4 fdot2 per quad.
__global__ void __launch_bounds__(256, 8) e1p2_kernel(
        const float* __restrict__ pos,
        const int* __restrict__ offsets, const int* __restrict__ sorted_src,
        const float2* __restrict__ g1,
        const float* __restrict__ W1_pos, const float* __restrict__ b1_pos,
        const float* __restrict__ W2_src, const float* __restrict__ W2_val,
        const float* __restrict__ W2_pos,
        float2* __restrict__ g2, int N) {
    __shared__ uint4 W4q[16 * 64];    // [q][c]: k-quad (s01,s23,v01,v23), 16KB
    __shared__ __half hsh[4][64];
    int tid = threadIdx.x, lane = tid & 63, wid = tid >> 6;
    for (int idx = tid; idx < 1024; idx += 256) {
        int q = idx >> 6, c = idx & 63, k = 4 * q;
        H2U s01, s23, v01, v23;
        s01.hh = __floats2half2_rn(W2_src[k * 64 + c], W2_src[(k + 1) * 64 + c]);
        s23.hh = __floats2half2_rn(W2_src[(k + 2) * 64 + c], W2_src[(k + 3) * 64 + c]);
        v01.hh = __floats2half2_rn(W2_val[k * 64 + c], W2_val[(k + 1) * 64 + c]);
        v23.hh = __floats2half2_rn(W2_val[(k + 2) * 64 + c], W2_val[(k + 3) * 64 + c]);
        W4q[idx] = make_uint4(s01.u, s23.u, v01.u, v23.u);
    }
    __syncthreads();

    float w1p0 = W1_pos[lane], w1p1 = W1_pos[64 + lane], w1p2 = W1_pos[128 + lane];
    float bp1 = b1_pos[lane];
    float w2p0 = W2_pos[lane], w2p1 = W2_pos[64 + lane], w2p2 = W2_pos[128 + lane];
    int laneoff = lane * 8;
    int nwav = gridDim.x * 4;

    for (int node = blockIdx.x * 4 + wid; node < N; node += nwav) {
        float p0 = pos[node * 3 + 0], p1 = pos[node * 3 + 1], p2 = pos[node * 3 + 2];
        float dpos = fmaf(p0, w1p0, fmaf(p1, w1p1, p2 * w1p2));
        float hval = edge_node(node, laneoff, offsets, sorted_src,
                               (const char*)g1, dpos + bp1);
        hsh[wid][lane] = __float2half(hval);   // same-wave publish (all lanes)
        const uint2* hq = (const uint2*)hsh[wid];
        float as = 0.f, vv = 0.f;
        #pragma unroll 4
        for (int q = 0; q < 16; ++q) {
            uint2 hu = hq[q];                  // broadcast b64: h quad
            H2U h01, h23; h01.u = hu.x; h23.u = hu.y;
            uint4 wq = W4q[q * 64 + lane];     // ds_read_b128
            H2U a0, a1, b0, b1;
            a0.u = wq.x; a1.u = wq.y; b0.u = wq.z; b1.u = wq.w;
            as = fdot2(h01.hf, a0.hf, as);
            as = fdot2(h23.hf, a1.hf, as);
            vv = fdot2(h01.hf, b0.hf, vv);
            vv = fdot2(h23.hf, b1.hf, vv);
        }
        float cc = fmaf(p0, w2p0, fmaf(p1, w2p1, p2 * w2p2));
        g2[node * 64 + lane] = pack_payload(as + cc, vv - cc);
    }
}

// E2 + fused relu/fc1/relu/fc2 head, grid-strided, fc1 via fdot2.
__global__ void __launch_bounds__(256, 8) e2head_kernel(
        const float* __restrict__ pos,
        const int* __restrict__ offsets, const int* __restrict__ sorted_src,
        const float2* __restrict__ g2,
        const float* __restrict__ W2_pos, const float* __restrict__ b2_pos,
        const float* __restrict__ Wfc1, const float* __restrict__ bfc1,
        const float* __restrict__ Wfc2, const float* __restrict__ bfc2,
        float* __restrict__ out, int N) {
    __shared__ unsigned Wf2[1024];    // [kk][c] fc1 k-pairs as half2 bits, 4KB
    __shared__ __half hsh[4][64];
    int tid = threadIdx.x, lane = tid & 63, wid = tid >> 6;
    for (int idx = tid; idx < 1024; idx += 256) {
        int kk = idx >> 5, c = idx & 31;
        H2U w;
        w.hh = __floats2half2_rn(Wfc1[(2 * kk) * 32 + c], Wfc1[(2 * kk + 1) * 32 + c]);
        Wf2[idx] = w.u;
    }
    __syncthreads();

    float wp0 = W2_pos[lane], wp1 = W2_pos[64 + lane], wp2 = W2_pos[128 + lane];
    float bp = b2_pos[lane];
    int c = lane & 31, khb = (lane >> 5) * 16;
    float bfc1c = bfc1[c], wfc2c = Wfc2[c], bias2 = bfc2[0];
    int laneoff = lane * 8;
    int nwav = gridDim.x * 4;

    for (int node = blockIdx.x * 4 + wid; node < N; node += nwav) {
        float p0 = pos[node * 3 + 0], p1 = pos[node * 3 + 1], p2 = pos[node * 3 + 2];
        float dpos = fmaf(p0, wp0, fmaf(p1, wp1, p2 * wp2));
        float hval = edge_node(node, laneoff, offsets, sorted_src,
                               (const char*)g2, dpos + bp);
        hsh[wid][lane] = __float2half(hval);   // all-lane same-wave publish
        const hf2* h2 = (const hf2*)hsh[wid];
        float t2 = 0.f;
        #pragma unroll 8
        for (int j = 0; j < 16; ++j) {
            hf2 hk = h2[khb + j];              // 4B broadcast read
            H2U w; w.u = Wf2[(khb + j) * 32 + c];
            t2 = fdot2(hk, w.hf, t2);
        }
        t2 += __shfl_down(t2, 32);             // all lanes execute
        t2 = fmaxf(t2 + bfc1c, 0.f) * wfc2c;
        t2 = (lane < 32) ? t2 : 0.f;
        #pragma unroll
        for (int off = 16; off >= 1; off >>= 1) t2 += __shfl_down(t2, off);
        if (lane == 0) out[node] = t2 + bias2;
    }
}

extern "C" void kernel_launch(void* const* d_in, const int* in_sizes, int n_in,
                              void* d_out, int out_size, void* d_ws, size_t ws_size,
                              hipStream_t stream) {
    const float* x   = (const float*)d_in[0];
    const float* pos = (const float*)d_in[1];
    const int* eidx  = (const int*)d_in[2];
    const float* W1_src = (const float*)d_in[4];
    // d_in[5] = W1_dst: cancels in softmax
    const float* W1_val = (const float*)d_in[6];
    const float* W1_pos = (const float*)d_in[7];
    const float* b1_pos = (const float*)d_in[8];
    const float* W2_src = (const float*)d_in[9];
    // d_in[10] = W2_dst: cancels in softmax
    const float* W2_val = (const float*)d_in[11];
    const float* W2_pos = (const float*)d_in[12];
    const float* b2_pos = (const float*)d_in[13];
    const float* W_fc1  = (const float*)d_in[14];
    const float* b_fc1  = (const float*)d_in[15];
    const float* W_fc2  = (const float*)d_in[16];
    const float* b_fc2  = (const float*)d_in[17];

    const int N = in_sizes[0] / 3;
    const int E = in_sizes[2] / 2;
    const int* src = eidx;
    const int* dst = eidx + E;
    const int nsb = (N + 1023) / 1024;   // 49 for N=50K

    char* w = (char*)d_ws;
    auto carve = [&](size_t bytes) -> void* {
        void* p = (void*)w;
        w += (bytes + 255) & ~size_t(255);
        return p;
    };
    int*    count      = (int*)carve((size_t)N * 4);
    int*    offsets    = (int*)carve((size_t)(N + 1) * 4);
    int*    rank       = (int*)carve((size_t)E * 4);
    int*    sorted_src = (int*)carve((size_t)E * 4);
    float2* g1         = (float2*)carve((size_t)N * 64 * 8);
    float2* g2         = (float2*)carve((size_t)N * 64 * 8);

    hipMemsetAsync(count, 0, (size_t)N * 4, stream);
    hist_proj1_kernel<<<2048, 256, 0, stream>>>(
        dst, count, rank, x, pos, W1_src, W1_val, W1_pos, g1, N, E);
    scan_kernel<<<nsb, 256, 0, stream>>>(count, offsets, N, nsb);
    scatter_kernel<<<(E + 255) / 256, 256, 0, stream>>>(src, dst, rank, offsets,
                                                        sorted_src, E);
    e1p2_kernel<<<2048, 256, 0, stream>>>(
        pos, offsets, sorted_src, g1, W1_pos, b1_pos, W2_src, W2_val, W2_pos, g2, N);
    e2head_kernel<<<2048, 256, 0, stream>>>(
        pos, offsets, sorted_src, g2, W2_pos, b2_pos,
        W_fc1, b_fc1, W_fc2, b_fc2, (float*)d_out, N);
}

// Round 11
// 251.115 us; speedup vs baseline: 1.0743x; 1.0743x over previous
//
#include <hip/hip_runtime.h>
#include <hip/hip_fp16.h>
#include <math.h>

// ---------------------------------------------------------------------------
// PointTransformerNet forward, 6 kernels + memset:
//   memset(count) ; hist+proj1 ; scan ; scatter ; E1+proj2 ; E2+head
//
// R11: edge payload is bf16x2 (E hi16, E*vv lo16), E = e^{-(a_src+c)} per src
// node. Factored softmax (per-dst exp cancels): h = relu(dv + sum(Ev)/sum(E)).
// bf16 keeps f32's exponent range (R9's f16 clamp failure impossible) at 4B --
// R8's gather bytes (R10's f32 8B payload went memory-bound, 43% HBM).
// Per edge: one 4B gather + and/shl unpack + two v_add_f32.
// e1p2 proj2-dot: W2 held in 64 VGPRs/lane (LDS->reg once per wave) -> per-node
// LDS is just 16 b64 h-broadcasts (was 16 b128 + 16 b64, ~20us of e1p2).
// e2head fc1: Wfc1 in 16 VGPRs from global once per wave, no LDS staging.
//
// R6: grid-stride, stage W once per block. R5: grid.sync ~200us -- never.
// ---------------------------------------------------------------------------

#define LOG2E 1.44269504088896340736f

typedef _Float16 hf2 __attribute__((ext_vector_type(2)));
union H2U { __half2 hh; hf2 hf; unsigned u; };

#if defined(__has_builtin)
#if __has_builtin(__builtin_amdgcn_fdot2)
#define HAVE_FDOT2 1
#endif
#endif

__device__ __forceinline__ float fdot2(hf2 a, hf2 b, float c) {
#ifdef HAVE_FDOT2
    return __builtin_amdgcn_fdot2(a, b, c, false);
#else
    return fmaf((float)a.x, (float)b.x, fmaf((float)a.y, (float)b.y, c));
#endif
}

__device__ __forceinline__ unsigned bf16_rn(float x) {
    unsigned b = __float_as_uint(x);
    return (b + 0x7FFFu + ((b >> 16) & 1u)) >> 16;   // round-to-nearest-even
}

// Payload: (E hi16, E*vv lo16) as bf16. Exponent clamp at +-86 (f32 inf guard
// only; |a+c| <= ~15 in practice so clamp is unreachable).
__device__ __forceinline__ unsigned pack_payload(float a_plus_c, float vv) {
    float t = fminf(fmaxf(-a_plus_c * LOG2E, -86.0f), 86.0f);
    float E = exp2f(t);
    return (bf16_rn(E) << 16) | bf16_rn(E * vv);
}

// hist (1 atomic/edge, rank recorded) + conv1 payload, grid-strided.
__global__ void __launch_bounds__(256) hist_proj1_kernel(
        const int* __restrict__ dst, int* __restrict__ count, int* __restrict__ rank,
        const float* __restrict__ x, const float* __restrict__ pos,
        const float* __restrict__ W1_src, const float* __restrict__ W1_val,
        const float* __restrict__ W1_pos,
        unsigned* __restrict__ g1, int N, int E) {
    int gtid = blockIdx.x * 256 + threadIdx.x;
    int gsz = gridDim.x * 256;
    for (int e = gtid; e < E; e += gsz)
        rank[e] = atomicAdd(&count[dst[e]], 1);

    int lane = threadIdx.x & 63, wid = threadIdx.x >> 6;
    float ws0 = W1_src[lane], ws1 = W1_src[64 + lane], ws2 = W1_src[128 + lane];
    float wv0 = W1_val[lane], wv1 = W1_val[64 + lane], wv2 = W1_val[128 + lane];
    float wp0 = W1_pos[lane], wp1 = W1_pos[64 + lane], wp2 = W1_pos[128 + lane];
    int nwav = gridDim.x * 4;
    for (int node = blockIdx.x * 4 + wid; node < N; node += nwav) {
        float x0 = x[node * 3 + 0], x1 = x[node * 3 + 1], x2 = x[node * 3 + 2];
        float p0 = pos[node * 3 + 0], p1 = pos[node * 3 + 1], p2 = pos[node * 3 + 2];
        float as = fmaf(x0, ws0, fmaf(x1, ws1, x2 * ws2));
        float vv = fmaf(x0, wv0, fmaf(x1, wv1, x2 * wv2));
        float cc = fmaf(p0, wp0, fmaf(p1, wp1, p2 * wp2));
        g1[node * 64 + lane] = pack_payload(as + cc, vv - cc);
    }
}

// Single-kernel scan: block b redundantly reduces count[0 .. b*1024) for its
// base, then emits its 1024-chunk's exclusive prefix.
__global__ void __launch_bounds__(256) scan_kernel(
        const int* __restrict__ count, int* __restrict__ offsets, int n, int nsb) {
    __shared__ int red[4];
    __shared__ int wpre[4];
    int tid = threadIdx.x, lane = tid & 63, wid = tid >> 6;
    int lim = blockIdx.x * 1024;
    int s = 0;
    for (int i = tid * 4; i < lim; i += 1024) {
        int4 c = *(const int4*)&count[i];
        s += c.x + c.y + c.z + c.w;
    }
    #pragma unroll
    for (int off = 32; off >= 1; off >>= 1) s += __shfl_down(s, off);
    if (lane == 0) red[wid] = s;
    __syncthreads();
    int base = red[0] + red[1] + red[2] + red[3];

    int b4 = lim + tid * 4;
    int4 c = make_int4(0, 0, 0, 0);
    if (b4 + 3 < n) {
        c = *(const int4*)&count[b4];
    } else {
        if (b4 + 0 < n) c.x = count[b4 + 0];
        if (b4 + 1 < n) c.y = count[b4 + 1];
        if (b4 + 2 < n) c.z = count[b4 + 2];
    }
    int tsum = c.x + c.y + c.z + c.w;
    int inc = tsum;
    #pragma unroll
    for (int off = 1; off < 64; off <<= 1) {
        int t2 = __shfl_up(inc, off);
        if (lane >= off) inc += t2;
    }
    if (lane == 63) wpre[wid] = inc;
    __syncthreads();
    int wbase = 0;
    for (int q = 0; q < wid; ++q) wbase += wpre[q];
    int excl = base + wbase + (inc - tsum);
    if (b4 + 0 < n) offsets[b4 + 0] = excl;
    if (b4 + 1 < n) offsets[b4 + 1] = excl + c.x;
    if (b4 + 2 < n) offsets[b4 + 2] = excl + c.x + c.y;
    if (b4 + 3 < n) offsets[b4 + 3] = excl + c.x + c.y + c.z;
    if ((int)blockIdx.x == nsb - 1 && tid == 0)
        offsets[n] = base + wpre[0] + wpre[1] + wpre[2] + wpre[3];
}

__global__ void __launch_bounds__(256) scatter_kernel(
        const int* __restrict__ src, const int* __restrict__ dst,
        const int* __restrict__ rank, const int* __restrict__ offsets,
        int* __restrict__ sorted_src, int E) {
    int e = blockIdx.x * 256 + threadIdx.x;
    if (e < E) sorted_src[offsets[dst[e]] + rank[e]] = src[e];
}

// Per-edge accumulate: unpack bf16x2 payload (and/shl) + two adds.
__device__ __forceinline__ void eacc(unsigned u, float& s, float& n) {
    s += __uint_as_float(u & 0xFFFF0000u);
    n += __uint_as_float(u << 16);
}

// Segment aggregate: returns relu(dv + sum(Ev)/sum(E)).
// Per edge: one 4B gather + 4 VALU. 8-deep pipelined, scalar addressing.
__device__ __forceinline__ float edge_node(
        int node, int laneoff,
        const int* __restrict__ offsets, const int* __restrict__ ss,
        const char* __restrict__ gbase, float dv) {
    int beg = offsets[node], end = offsets[node + 1];
    if (beg >= end) return 0.f;           // degree-0: reference gives 0
    float s0 = 0.f, n0 = 0.f, s1 = 0.f, n1 = 0.f;
    int e = beg;
    int aligned = min((beg + 3) & ~3, end);    // peel to 16B alignment of ss
    for (; e < aligned; ++e) {
        int i0 = __builtin_amdgcn_readfirstlane(ss[e]);
        unsigned g0 = *(const unsigned*)(gbase + (((size_t)(unsigned)i0) << 8) + laneoff);
        eacc(g0, s0, n0);
    }
    for (; e + 8 <= end; e += 8) {
        int4 ia = *(const int4*)(ss + e);
        int4 ib = *(const int4*)(ss + e + 4);
        int i0 = __builtin_amdgcn_readfirstlane(ia.x);
        int i1 = __builtin_amdgcn_readfirstlane(ia.y);
        int i2 = __builtin_amdgcn_readfirstlane(ia.z);
        int i3 = __builtin_amdgcn_readfirstlane(ia.w);
        int i4 = __builtin_amdgcn_readfirstlane(ib.x);
        int i5 = __builtin_amdgcn_readfirstlane(ib.y);
        int i6 = __builtin_amdgcn_readfirstlane(ib.z);
        int i7 = __builtin_amdgcn_readfirstlane(ib.w);
        unsigned g0 = *(const unsigned*)(gbase + (((size_t)(unsigned)i0) << 8) + laneoff);
        unsigned g1 = *(const unsigned*)(gbase + (((size_t)(unsigned)i1) << 8) + laneoff);
        unsigned g2 = *(const unsigned*)(gbase + (((size_t)(unsigned)i2) << 8) + laneoff);
        unsigned g3 = *(const unsigned*)(gbase + (((size_t)(unsigned)i3) << 8) + laneoff);
        unsigned g4 = *(const unsigned*)(gbase + (((size_t)(unsigned)i4) << 8) + laneoff);
        unsigned g5 = *(const unsigned*)(gbase + (((size_t)(unsigned)i5) << 8) + laneoff);
        unsigned g6 = *(const unsigned*)(gbase + (((size_t)(unsigned)i6) << 8) + laneoff);
        unsigned g7 = *(const unsigned*)(gbase + (((size_t)(unsigned)i7) << 8) + laneoff);
        eacc(g0, s0, n0);
        eacc(g1, s1, n1);
        eacc(g2, s0, n0);
        eacc(g3, s1, n1);
        eacc(g4, s0, n0);
        eacc(g5, s1, n1);
        eacc(g6, s0, n0);
        eacc(g7, s1, n1);
    }
    for (; e + 4 <= end; e += 4) {
        int4 ia = *(const int4*)(ss + e);
        int i0 = __builtin_amdgcn_readfirstlane(ia.x);
        int i1 = __builtin_amdgcn_readfirstlane(ia.y);
        int i2 = __builtin_amdgcn_readfirstlane(ia.z);
        int i3 = __builtin_amdgcn_readfirstlane(ia.w);
        unsigned g0 = *(const unsigned*)(gbase + (((size_t)(unsigned)i0) << 8) + laneoff);
        unsigned g1 = *(const unsigned*)(gbase + (((size_t)(unsigned)i1) << 8) + laneoff);
        unsigned g2 = *(const unsigned*)(gbase + (((size_t)(unsigned)i2) << 8) + laneoff);
        unsigned g3 = *(const unsigned*)(gbase + (((size_t)(unsigned)i3) << 8) + laneoff);
        eacc(g0, s0, n0);
        eacc(g1, s1, n1);
        eacc(g2, s0, n0);
        eacc(g3, s1, n1);
    }
    for (; e < end; ++e) {
        int i0 = __builtin_amdgcn_readfirstlane(ss[e]);
        unsigned g0 = *(const unsigned*)(gbase + (((size_t)(unsigned)i0) << 8) + laneoff);
        eacc(g0, s0, n0);
    }
    float s = s0 + s1;
    float r = __builtin_amdgcn_rcpf(s + 1e-37f);
    return fmaxf(fmaf(n0 + n1, r, dv), 0.f);
}

// E1 + proj2 fused, grid-strided. W2 k-quads (s01,s23,v01,v23) staged to LDS
// once per block, then copied into 64 VGPRs per lane -> per-node LDS traffic
// is only the 16 b64 h-broadcast reads. launch_bounds(256,4): ~100 VGPRs.
__global__ void __launch_bounds__(256, 4) e1p2_kernel(
        const float* __restrict__ pos,
        const int* __restrict__ offsets, const int* __restrict__ sorted_src,
        const unsigned* __restrict__ g1,
        const float* __restrict__ W1_pos, const float* __restrict__ b1_pos,
        const float* __restrict__ W2_src, const float* __restrict__ W2_val,
        const float* __restrict__ W2_pos,
        unsigned* __restrict__ g2, int N) {
    __shared__ uint4 W4q[16 * 64];    // [q][c]: k-quad (s01,s23,v01,v23), 16KB
    __shared__ __half hsh[4][64];
    int tid = threadIdx.x, lane = tid & 63, wid = tid >> 6;
    for (int idx = tid; idx < 1024; idx += 256) {
        int q = idx >> 6, c = idx & 63, k = 4 * q;
        H2U s01, s23, v01, v23;
        s01.hh = __floats2half2_rn(W2_src[k * 64 + c], W2_src[(k + 1) * 64 + c]);
        s23.hh = __floats2half2_rn(W2_src[(k + 2) * 64 + c], W2_src[(k + 3) * 64 + c]);
        v01.hh = __floats2half2_rn(W2_val[k * 64 + c], W2_val[(k + 1) * 64 + c]);
        v23.hh = __floats2half2_rn(W2_val[(k + 2) * 64 + c], W2_val[(k + 3) * 64 + c]);
        W4q[idx] = make_uint4(s01.u, s23.u, v01.u, v23.u);
    }
    __syncthreads();
    uint4 Wr[16];                     // 64 VGPRs: this lane's W2 column quads
    #pragma unroll
    for (int q = 0; q < 16; ++q) Wr[q] = W4q[q * 64 + lane];

    float w1p0 = W1_pos[lane], w1p1 = W1_pos[64 + lane], w1p2 = W1_pos[128 + lane];
    float bp1 = b1_pos[lane];
    float w2p0 = W2_pos[lane], w2p1 = W2_pos[64 + lane], w2p2 = W2_pos[128 + lane];
    int laneoff = lane * 4;
    int nwav = gridDim.x * 4;

    for (int node = blockIdx.x * 4 + wid; node < N; node += nwav) {
        float p0 = pos[node * 3 + 0], p1 = pos[node * 3 + 1], p2 = pos[node * 3 + 2];
        float dpos = fmaf(p0, w1p0, fmaf(p1, w1p1, p2 * w1p2));
        float hval = edge_node(node, laneoff, offsets, sorted_src,
                               (const char*)g1, dpos + bp1);
        hsh[wid][lane] = __float2half(hval);   // same-wave publish (all lanes)
        const uint2* hq = (const uint2*)hsh[wid];
        float as = 0.f, vv = 0.f;
        #pragma unroll
        for (int q = 0; q < 16; ++q) {
            uint2 hu = hq[q];                  // b64 broadcast: h quad
            H2U h01, h23; h01.u = hu.x; h23.u = hu.y;
            H2U a0, a1, b0, b1;
            a0.u = Wr[q].x; a1.u = Wr[q].y; b0.u = Wr[q].z; b1.u = Wr[q].w;
            as = fdot2(h01.hf, a0.hf, as);
            as = fdot2(h23.hf, a1.hf, as);
            vv = fdot2(h01.hf, b0.hf, vv);
            vv = fdot2(h23.hf, b1.hf, vv);
        }
        float cc = fmaf(p0, w2p0, fmaf(p1, w2p1, p2 * w2p2));
        g2[node * 64 + lane] = pack_payload(as + cc, vv - cc);
    }
}

// E2 + fused relu/fc1/relu/fc2 head, grid-strided. fc1 via fdot2 with Wfc1
// pairs held in 16 VGPRs (loaded from global once per wave, no LDS staging).
__global__ void __launch_bounds__(256, 8) e2head_kernel(
        const float* __restrict__ pos,
        const int* __restrict__ offsets, const int* __restrict__ sorted_src,
        const unsigned* __restrict__ g2,
        const float* __restrict__ W2_pos, const float* __restrict__ b2_pos,
        const float* __restrict__ Wfc1, const float* __restrict__ bfc1,
        const float* __restrict__ Wfc2, const float* __restrict__ bfc2,
        float* __restrict__ out, int N) {
    __shared__ __half hsh[4][64];
    int tid = threadIdx.x, lane = tid & 63, wid = tid >> 6;
    int c = lane & 31, khb = (lane >> 5) * 16;
    unsigned Wr[16];                  // this lane's fc1 k-pairs (16 VGPRs)
    #pragma unroll
    for (int j = 0; j < 16; ++j) {
        H2U w;
        w.hh = __floats2half2_rn(Wfc1[(2 * (khb + j)) * 32 + c],
                                 Wfc1[(2 * (khb + j) + 1) * 32 + c]);
        Wr[j] = w.u;
    }

    float wp0 = W2_pos[lane], wp1 = W2_pos[64 + lane], wp2 = W2_pos[128 + lane];
    float bp = b2_pos[lane];
    float bfc1c = bfc1[c], wfc2c = Wfc2[c], bias2 = bfc2[0];
    int laneoff = lane * 4;
    int nwav = gridDim.x * 4;

    for (int node = blockIdx.x * 4 + wid; node < N; node += nwav) {
        float p0 = pos[node * 3 + 0], p1 = pos[node * 3 + 1], p2 = pos[node * 3 + 2];
        float dpos = fmaf(p0, wp0, fmaf(p1, wp1, p2 * wp2));
        float hval = edge_node(node, laneoff, offsets, sorted_src,
                               (const char*)g2, dpos + bp);
        hsh[wid][lane] = __float2half(hval);   // all-lane same-wave publish
        const hf2* h2 = (const hf2*)hsh[wid];
        float t2 = 0.f;
        #pragma unroll
        for (int j = 0; j < 16; ++j) {
            hf2 hk = h2[khb + j];              // 4B broadcast read
            H2U w; w.u = Wr[j];
            t2 = fdot2(hk, w.hf, t2);
        }
        t2 += __shfl_down(t2, 32);             // all lanes execute
        t2 = fmaxf(t2 + bfc1c, 0.f) * wfc2c;
        t2 = (lane < 32) ? t2 : 0.f;
        #pragma unroll
        for (int off = 16; off >= 1; off >>= 1) t2 += __shfl_down(t2, off);
        if (lane == 0) out[node] = t2 + bias2;
    }
}

extern "C" void kernel_launch(void* const* d_in, const int* in_sizes, int n_in,
                              void* d_out, int out_size, void* d_ws, size_t ws_size,
                              hipStream_t stream) {
    const float* x   = (const float*)d_in[0];
    const float* pos = (const float*)d_in[1];
    const int* eidx  = (const int*)d_in[2];
    const float* W1_src = (const float*)d_in[4];
    // d_in[5] = W1_dst: cancels in softmax
    const float* W1_val = (const float*)d_in[6];
    const float* W1_pos = (const float*)d_in[7];
    const float* b1_pos = (const float*)d_in[8];
    const float* W2_src = (const float*)d_in[9];
    // d_in[10] = W2_dst: cancels in softmax
    const float* W2_val = (const float*)d_in[11];
    const float* W2_pos = (const float*)d_in[12];
    const float* b2_pos = (const float*)d_in[13];
    const float* W_fc1  = (const float*)d_in[14];
    const float* b_fc1  = (const float*)d_in[15];
    const float* W_fc2  = (const float*)d_in[16];
    const float* b_fc2  = (const float*)d_in[17];

    const int N = in_sizes[0] / 3;
    const int E = in_sizes[2] / 2;
    const int* src = eidx;
    const int* dst = eidx + E;
    const int nsb = (N + 1023) / 1024;   // 49 for N=50K

    char* w = (char*)d_ws;
    auto carve = [&](size_t bytes) -> void* {
        void* p = (void*)w;
        w += (bytes + 255) & ~size_t(255);
        return p;
    };
    int*      count      = (int*)carve((size_t)N * 4);
    int*      offsets    = (int*)carve((size_t)(N + 1) * 4);
    int*      rank       = (int*)carve((size_t)E * 4);
    int*      sorted_src = (int*)carve((size_t)E * 4);
    unsigned* g1         = (unsigned*)carve((size_t)N * 64 * 4);
    unsigned* g2         = (unsigned*)carve((size_t)N * 64 * 4);

    hipMemsetAsync(count, 0, (size_t)N * 4, stream);
    hist_proj1_kernel<<<2048, 256, 0, stream>>>(
        dst, count, rank, x, pos, W1_src, W1_val, W1_pos, g1, N, E);
    scan_kernel<<<nsb, 256, 0, stream>>>(count, offsets, N, nsb);
    scatter_kernel<<<(E + 255) / 256, 256, 0, stream>>>(src, dst, rank, offsets,
                                                        sorted_src, E);
    e1p2_kernel<<<2048, 256, 0, stream>>>(
        pos, offsets, sorted_src, g1, W1_pos, b1_pos, W2_src, W2_val, W2_pos, g2, N);
    e2head_kernel<<<2048, 256, 0, stream>>>(
        pos, offsets, sorted_src, g2, W2_pos, b2_pos,
        W_fc1, b_fc1, W_fc2, b_fc2, (float*)d_out, N);
}

// Round 12
// 231.549 us; speedup vs baseline: 1.1651x; 1.0845x over previous
//
#include <hip/hip_runtime.h>
#include <hip/hip_fp16.h>
#include <math.h>

// ---------------------------------------------------------------------------
// PointTransformerNet forward, 6 kernels + memset:
//   memset(count) ; hist+proj1 ; scan ; scatter ; E1+proj2 ; E2+head
//
// R12 = best-of: bf16x2 payload (R11) + LDS b128-quad proj2 dot (R10) +
// launch_bounds(256,8) occupancy (R8). R11 A/B proved: register-staging W2
// (uint4 Wr[16]) is DEFEATED by the compiler (VGPR=56 < 64 needed) and
// launch_bounds(256,4) drops occupancy 59->35% -> latency-bound edge loop
// loses hiding (+11us). Occupancy beats per-node instruction count here.
//
// Payload: bf16x2 (E hi16, E*vv lo16), E = e^{-(a_src+c)} per src node.
// Factored softmax (per-dst exp cancels): h = relu(dv + sum(Ev)/sum(E)).
// bf16 keeps f32's exponent range (R9's f16 clamp failure impossible) at the
// 4B gather size (R10's 8B f32 payload went memory-bound at 43% HBM).
// Per edge: one 4B gather + and/shl unpack + two v_add_f32.
//
// R6: grid-stride, stage W once per block. R5: grid.sync ~200us -- never.
// ---------------------------------------------------------------------------

#define LOG2E 1.44269504088896340736f

typedef _Float16 hf2 __attribute__((ext_vector_type(2)));
union H2U { __half2 hh; hf2 hf; unsigned u; };

#if defined(__has_builtin)
#if __has_builtin(__builtin_amdgcn_fdot2)
#define HAVE_FDOT2 1
#endif
#endif

__device__ __forceinline__ float fdot2(hf2 a, hf2 b, float c) {
#ifdef HAVE_FDOT2
    return __builtin_amdgcn_fdot2(a, b, c, false);
#else
    return fmaf((float)a.x, (float)b.x, fmaf((float)a.y, (float)b.y, c));
#endif
}

__device__ __forceinline__ unsigned bf16_rn(float x) {
    unsigned b = __float_as_uint(x);
    return (b + 0x7FFFu + ((b >> 16) & 1u)) >> 16;   // round-to-nearest-even
}

// Payload: (E hi16, E*vv lo16) as bf16. Clamp at +-86 is an f32-inf guard
// only (|a+c| <= ~15 in practice).
__device__ __forceinline__ unsigned pack_payload(float a_plus_c, float vv) {
    float t = fminf(fmaxf(-a_plus_c * LOG2E, -86.0f), 86.0f);
    float E = exp2f(t);
    return (bf16_rn(E) << 16) | bf16_rn(E * vv);
}

// hist (1 atomic/edge, rank recorded) + conv1 payload, grid-strided.
__global__ void __launch_bounds__(256) hist_proj1_kernel(
        const int* __restrict__ dst, int* __restrict__ count, int* __restrict__ rank,
        const float* __restrict__ x, const float* __restrict__ pos,
        const float* __restrict__ W1_src, const float* __restrict__ W1_val,
        const float* __restrict__ W1_pos,
        unsigned* __restrict__ g1, int N, int E) {
    int gtid = blockIdx.x * 256 + threadIdx.x;
    int gsz = gridDim.x * 256;
    for (int e = gtid; e < E; e += gsz)
        rank[e] = atomicAdd(&count[dst[e]], 1);

    int lane = threadIdx.x & 63, wid = threadIdx.x >> 6;
    float ws0 = W1_src[lane], ws1 = W1_src[64 + lane], ws2 = W1_src[128 + lane];
    float wv0 = W1_val[lane], wv1 = W1_val[64 + lane], wv2 = W1_val[128 + lane];
    float wp0 = W1_pos[lane], wp1 = W1_pos[64 + lane], wp2 = W1_pos[128 + lane];
    int nwav = gridDim.x * 4;
    for (int node = blockIdx.x * 4 + wid; node < N; node += nwav) {
        float x0 = x[node * 3 + 0], x1 = x[node * 3 + 1], x2 = x[node * 3 + 2];
        float p0 = pos[node * 3 + 0], p1 = pos[node * 3 + 1], p2 = pos[node * 3 + 2];
        float as = fmaf(x0, ws0, fmaf(x1, ws1, x2 * ws2));
        float vv = fmaf(x0, wv0, fmaf(x1, wv1, x2 * wv2));
        float cc = fmaf(p0, wp0, fmaf(p1, wp1, p2 * wp2));
        g1[node * 64 + lane] = pack_payload(as + cc, vv - cc);
    }
}

// Single-kernel scan: block b redundantly reduces count[0 .. b*1024) for its
// base, then emits its 1024-chunk's exclusive prefix.
__global__ void __launch_bounds__(256) scan_kernel(
        const int* __restrict__ count, int* __restrict__ offsets, int n, int nsb) {
    __shared__ int red[4];
    __shared__ int wpre[4];
    int tid = threadIdx.x, lane = tid & 63, wid = tid >> 6;
    int lim = blockIdx.x * 1024;
    int s = 0;
    for (int i = tid * 4; i < lim; i += 1024) {
        int4 c = *(const int4*)&count[i];
        s += c.x + c.y + c.z + c.w;
    }
    #pragma unroll
    for (int off = 32; off >= 1; off >>= 1) s += __shfl_down(s, off);
    if (lane == 0) red[wid] = s;
    __syncthreads();
    int base = red[0] + red[1] + red[2] + red[3];

    int b4 = lim + tid * 4;
    int4 c = make_int4(0, 0, 0, 0);
    if (b4 + 3 < n) {
        c = *(const int4*)&count[b4];
    } else {
        if (b4 + 0 < n) c.x = count[b4 + 0];
        if (b4 + 1 < n) c.y = count[b4 + 1];
        if (b4 + 2 < n) c.z = count[b4 + 2];
    }
    int tsum = c.x + c.y + c.z + c.w;
    int inc = tsum;
    #pragma unroll
    for (int off = 1; off < 64; off <<= 1) {
        int t2 = __shfl_up(inc, off);
        if (lane >= off) inc += t2;
    }
    if (lane == 63) wpre[wid] = inc;
    __syncthreads();
    int wbase = 0;
    for (int q = 0; q < wid; ++q) wbase += wpre[q];
    int excl = base + wbase + (inc - tsum);
    if (b4 + 0 < n) offsets[b4 + 0] = excl;
    if (b4 + 1 < n) offsets[b4 + 1] = excl + c.x;
    if (b4 + 2 < n) offsets[b4 + 2] = excl + c.x + c.y;
    if (b4 + 3 < n) offsets[b4 + 3] = excl + c.x + c.y + c.z;
    if ((int)blockIdx.x == nsb - 1 && tid == 0)
        offsets[n] = base + wpre[0] + wpre[1] + wpre[2] + wpre[3];
}

__global__ void __launch_bounds__(256) scatter_kernel(
        const int* __restrict__ src, const int* __restrict__ dst,
        const int* __restrict__ rank, const int* __restrict__ offsets,
        int* __restrict__ sorted_src, int E) {
    int e = blockIdx.x * 256 + threadIdx.x;
    if (e < E) sorted_src[offsets[dst[e]] + rank[e]] = src[e];
}

// Per-edge accumulate: unpack bf16x2 payload (and/shl) + two adds.
__device__ __forceinline__ void eacc(unsigned u, float& s, float& n) {
    s += __uint_as_float(u & 0xFFFF0000u);
    n += __uint_as_float(u << 16);
}

// Segment aggregate: returns relu(dv + sum(Ev)/sum(E)).
// Per edge: one 4B gather + 4 VALU. 8-deep pipelined, scalar addressing.
__device__ __forceinline__ float edge_node(
        int node, int laneoff,
        const int* __restrict__ offsets, const int* __restrict__ ss,
        const char* __restrict__ gbase, float dv) {
    int beg = offsets[node], end = offsets[node + 1];
    if (beg >= end) return 0.f;           // degree-0: reference gives 0
    float s0 = 0.f, n0 = 0.f, s1 = 0.f, n1 = 0.f;
    int e = beg;
    int aligned = min((beg + 3) & ~3, end);    // peel to 16B alignment of ss
    for (; e < aligned; ++e) {
        int i0 = __builtin_amdgcn_readfirstlane(ss[e]);
        unsigned g0 = *(const unsigned*)(gbase + (((size_t)(unsigned)i0) << 8) + laneoff);
        eacc(g0, s0, n0);
    }
    for (; e + 8 <= end; e += 8) {
        int4 ia = *(const int4*)(ss + e);
        int4 ib = *(const int4*)(ss + e + 4);
        int i0 = __builtin_amdgcn_readfirstlane(ia.x);
        int i1 = __builtin_amdgcn_readfirstlane(ia.y);
        int i2 = __builtin_amdgcn_readfirstlane(ia.z);
        int i3 = __builtin_amdgcn_readfirstlane(ia.w);
        int i4 = __builtin_amdgcn_readfirstlane(ib.x);
        int i5 = __builtin_amdgcn_readfirstlane(ib.y);
        int i6 = __builtin_amdgcn_readfirstlane(ib.z);
        int i7 = __builtin_amdgcn_readfirstlane(ib.w);
        unsigned g0 = *(const unsigned*)(gbase + (((size_t)(unsigned)i0) << 8) + laneoff);
        unsigned g1 = *(const unsigned*)(gbase + (((size_t)(unsigned)i1) << 8) + laneoff);
        unsigned g2 = *(const unsigned*)(gbase + (((size_t)(unsigned)i2) << 8) + laneoff);
        unsigned g3 = *(const unsigned*)(gbase + (((size_t)(unsigned)i3) << 8) + laneoff);
        unsigned g4 = *(const unsigned*)(gbase + (((size_t)(unsigned)i4) << 8) + laneoff);
        unsigned g5 = *(const unsigned*)(gbase + (((size_t)(unsigned)i5) << 8) + laneoff);
        unsigned g6 = *(const unsigned*)(gbase + (((size_t)(unsigned)i6) << 8) + laneoff);
        unsigned g7 = *(const unsigned*)(gbase + (((size_t)(unsigned)i7) << 8) + laneoff);
        eacc(g0, s0, n0);
        eacc(g1, s1, n1);
        eacc(g2, s0, n0);
        eacc(g3, s1, n1);
        eacc(g4, s0, n0);
        eacc(g5, s1, n1);
        eacc(g6, s0, n0);
        eacc(g7, s1, n1);
    }
    for (; e + 4 <= end; e += 4) {
        int4 ia = *(const int4*)(ss + e);
        int i0 = __builtin_amdgcn_readfirstlane(ia.x);
        int i1 = __builtin_amdgcn_readfirstlane(ia.y);
        int i2 = __builtin_amdgcn_readfirstlane(ia.z);
        int i3 = __builtin_amdgcn_readfirstlane(ia.w);
        unsigned g0 = *(const unsigned*)(gbase + (((size_t)(unsigned)i0) << 8) + laneoff);
        unsigned g1 = *(const unsigned*)(gbase + (((size_t)(unsigned)i1) << 8) + laneoff);
        unsigned g2 = *(const unsigned*)(gbase + (((size_t)(unsigned)i2) << 8) + laneoff);
        unsigned g3 = *(const unsigned*)(gbase + (((size_t)(unsigned)i3) << 8) + laneoff);
        eacc(g0, s0, n0);
        eacc(g1, s1, n1);
        eacc(g2, s0, n0);
        eacc(g3, s1, n1);
    }
    for (; e < end; ++e) {
        int i0 = __builtin_amdgcn_readfirstlane(ss[e]);
        unsigned g0 = *(const unsigned*)(gbase + (((size_t)(unsigned)i0) << 8) + laneoff);
        eacc(g0, s0, n0);
    }
    float s = s0 + s1;
    float r = __builtin_amdgcn_rcpf(s + 1e-37f);
    return fmaxf(fmaf(n0 + n1, r, dv), 0.f);
}

// E1 + proj2 fused, grid-strided, launch_bounds(256,8) (R8-proven occupancy).
// proj2 dot: W2 staged in LDS as b128 k-quads (s01,s23,v01,v23); per node:
// 16 ds_read_b128 + 16 b64 h-broadcasts + 64 fdot2.
__global__ void __launch_bounds__(256, 8) e1p2_kernel(
        const float* __restrict__ pos,
        const int* __restrict__ offsets, const int* __restrict__ sorted_src,
        const unsigned* __restrict__ g1,
        const float* __restrict__ W1_pos, const float* __restrict__ b1_pos,
        const float* __restrict__ W2_src, const float* __restrict__ W2_val,
        const float* __restrict__ W2_pos,
        unsigned* __restrict__ g2, int N) {
    __shared__ uint4 W4q[16 * 64];    // [q][c]: k-quad (s01,s23,v01,v23), 16KB
    __shared__ __half hsh[4][64];
    int tid = threadIdx.x, lane = tid & 63, wid = tid >> 6;
    for (int idx = tid; idx < 1024; idx += 256) {
        int q = idx >> 6, c = idx & 63, k = 4 * q;
        H2U s01, s23, v01, v23;
        s01.hh = __floats2half2_rn(W2_src[k * 64 + c], W2_src[(k + 1) * 64 + c]);
        s23.hh = __floats2half2_rn(W2_src[(k + 2) * 64 + c], W2_src[(k + 3) * 64 + c]);
        v01.hh = __floats2half2_rn(W2_val[k * 64 + c], W2_val[(k + 1) * 64 + c]);
        v23.hh = __floats2half2_rn(W2_val[(k + 2) * 64 + c], W2_val[(k + 3) * 64 + c]);
        W4q[idx] = make_uint4(s01.u, s23.u, v01.u, v23.u);
    }
    __syncthreads();

    float w1p0 = W1_pos[lane], w1p1 = W1_pos[64 + lane], w1p2 = W1_pos[128 + lane];
    float bp1 = b1_pos[lane];
    float w2p0 = W2_pos[lane], w2p1 = W2_pos[64 + lane], w2p2 = W2_pos[128 + lane];
    int laneoff = lane * 4;
    int nwav = gridDim.x * 4;

    for (int node = blockIdx.x * 4 + wid; node < N; node += nwav) {
        float p0 = pos[node * 3 + 0], p1 = pos[node * 3 + 1], p2 = pos[node * 3 + 2];
        float dpos = fmaf(p0, w1p0, fmaf(p1, w1p1, p2 * w1p2));
        float hval = edge_node(node, laneoff, offsets, sorted_src,
                               (const char*)g1, dpos + bp1);
        hsh[wid][lane] = __float2half(hval);   // same-wave publish (all lanes)
        const uint2* hq = (const uint2*)hsh[wid];
        float as = 0.f, vv = 0.f;
        #pragma unroll 4
        for (int q = 0; q < 16; ++q) {
            uint2 hu = hq[q];                  // b64 broadcast: h quad
            H2U h01, h23; h01.u = hu.x; h23.u = hu.y;
            uint4 wq = W4q[q * 64 + lane];     // ds_read_b128
            H2U a0, a1, b0, b1;
            a0.u = wq.x; a1.u = wq.y; b0.u = wq.z; b1.u = wq.w;
            as = fdot2(h01.hf, a0.hf, as);
            as = fdot2(h23.hf, a1.hf, as);
            vv = fdot2(h01.hf, b0.hf, vv);
            vv = fdot2(h23.hf, b1.hf, vv);
        }
        float cc = fmaf(p0, w2p0, fmaf(p1, w2p1, p2 * w2p2));
        g2[node * 64 + lane] = pack_payload(as + cc, vv - cc);
    }
}

// E2 + fused relu/fc1/relu/fc2 head, grid-strided. fc1 via fdot2 with Wfc1
// pairs held in 16 VGPRs (fits the 64-VGPR budget at 8 waves/EU).
__global__ void __launch_bounds__(256, 8) e2head_kernel(
        const float* __restrict__ pos,
        const int* __restrict__ offsets, const int* __restrict__ sorted_src,
        const unsigned* __restrict__ g2,
        const float* __restrict__ W2_pos, const float* __restrict__ b2_pos,
        const float* __restrict__ Wfc1, const float* __restrict__ bfc1,
        const float* __restrict__ Wfc2, const float* __restrict__ bfc2,
        float* __restrict__ out, int N) {
    __shared__ __half hsh[4][64];
    int tid = threadIdx.x, lane = tid & 63, wid = tid >> 6;
    int c = lane & 31, khb = (lane >> 5) * 16;
    unsigned Wr[16];                  // this lane's fc1 k-pairs (16 VGPRs)
    #pragma unroll
    for (int j = 0; j < 16; ++j) {
        H2U w;
        w.hh = __floats2half2_rn(Wfc1[(2 * (khb + j)) * 32 + c],
                                 Wfc1[(2 * (khb + j) + 1) * 32 + c]);
        Wr[j] = w.u;
    }

    float wp0 = W2_pos[lane], wp1 = W2_pos[64 + lane], wp2 = W2_pos[128 + lane];
    float bp = b2_pos[lane];
    float bfc1c = bfc1[c], wfc2c = Wfc2[c], bias2 = bfc2[0];
    int laneoff = lane * 4;
    int nwav = gridDim.x * 4;

    for (int node = blockIdx.x * 4 + wid; node < N; node += nwav) {
        float p0 = pos[node * 3 + 0], p1 = pos[node * 3 + 1], p2 = pos[node * 3 + 2];
        float dpos = fmaf(p0, wp0, fmaf(p1, wp1, p2 * wp2));
        float hval = edge_node(node, laneoff, offsets, sorted_src,
                               (const char*)g2, dpos + bp);
        hsh[wid][lane] = __float2half(hval);   // all-lane same-wave publish
        const hf2* h2 = (const hf2*)hsh[wid];
        float t2 = 0.f;
        #pragma unroll
        for (int j = 0; j < 16; ++j) {
            hf2 hk = h2[khb + j];              // 4B broadcast read
            H2U w; w.u = Wr[j];
            t2 = fdot2(hk, w.hf, t2);
        }
        t2 += __shfl_down(t2, 32);             // all lanes execute
        t2 = fmaxf(t2 + bfc1c, 0.f) * wfc2c;
        t2 = (lane < 32) ? t2 : 0.f;
        #pragma unroll
        for (int off = 16; off >= 1; off >>= 1) t2 += __shfl_down(t2, off);
        if (lane == 0) out[node] = t2 + bias2;
    }
}

extern "C" void kernel_launch(void* const* d_in, const int* in_sizes, int n_in,
                              void* d_out, int out_size, void* d_ws, size_t ws_size,
                              hipStream_t stream) {
    const float* x   = (const float*)d_in[0];
    const float* pos = (const float*)d_in[1];
    const int* eidx  = (const int*)d_in[2];
    const float* W1_src = (const float*)d_in[4];
    // d_in[5] = W1_dst: cancels in softmax
    const float* W1_val = (const float*)d_in[6];
    const float* W1_pos = (const float*)d_in[7];
    const float* b1_pos = (const float*)d_in[8];
    const float* W2_src = (const float*)d_in[9];
    // d_in[10] = W2_dst: cancels in softmax
    const float* W2_val = (const float*)d_in[11];
    const float* W2_pos = (const float*)d_in[12];
    const float* b2_pos = (const float*)d_in[13];
    const float* W_fc1  = (const float*)d_in[14];
    const float* b_fc1  = (const float*)d_in[15];
    const float* W_fc2  = (const float*)d_in[16];
    const float* b_fc2  = (const float*)d_in[17];

    const int N = in_sizes[0] / 3;
    const int E = in_sizes[2] / 2;
    const int* src = eidx;
    const int* dst = eidx + E;
    const int nsb = (N + 1023) / 1024;   // 49 for N=50K

    char* w = (char*)d_ws;
    auto carve = [&](size_t bytes) -> void* {
        void* p = (void*)w;
        w += (bytes + 255) & ~size_t(255);
        return p;
    };
    int*      count      = (int*)carve((size_t)N * 4);
    int*      offsets    = (int*)carve((size_t)(N + 1) * 4);
    int*      rank       = (int*)carve((size_t)E * 4);
    int*      sorted_src = (int*)carve((size_t)E * 4);
    unsigned* g1         = (unsigned*)carve((size_t)N * 64 * 4);
    unsigned* g2         = (unsigned*)carve((size_t)N * 64 * 4);

    hipMemsetAsync(count, 0, (size_t)N * 4, stream);
    hist_proj1_kernel<<<2048, 256, 0, stream>>>(
        dst, count, rank, x, pos, W1_src, W1_val, W1_pos, g1, N, E);
    scan_kernel<<<nsb, 256, 0, stream>>>(count, offsets, N, nsb);
    scatter_kernel<<<(E + 255) / 256, 256, 0, stream>>>(src, dst, rank, offsets,
                                                        sorted_src, E);
    e1p2_kernel<<<2048, 256, 0, stream>>>(
        pos, offsets, sorted_src, g1, W1_pos, b1_pos, W2_src, W2_val, W2_pos, g2, N);
    e2head_kernel<<<2048, 256, 0, stream>>>(
        pos, offsets, sorted_src, g2, W2_pos, b2_pos,
        W_fc1, b_fc1, W_fc2, b_fc2, (float*)d_out, N);
}